// Round 6
// baseline (191.390 us; speedup 1.0000x reference)
//
#include <hip/hip_runtime.h>

// CrossAttention on MI355X (gfx950), round 6.
// B=8 SQ=4096 SKV=77 DE=512 DC=768 H=8 DH=64.
// R6: qproj_attn v4 — barrier-free direct-from-global K-loop. A (fp32) and B
// (bf16) fragments are loaded straight to VGPRs (no LDS staging, no
// __syncthreads anywhere in the kernel); A packed to bf16 via
// v_cvt_pk_bf16_f32. P buffer moved inside each wave's own dead Qw region
// (wave-private) so the attn tail needs no barriers either.

typedef __attribute__((ext_vector_type(8))) __bf16 bf16x8;
typedef __attribute__((ext_vector_type(4))) float f32x4;

#define DEVI static __device__ __forceinline__

typedef __attribute__((address_space(3))) void lds_void_t;
typedef const __attribute__((address_space(1))) void gbl_void_t;
#define GLDS16(gsrc, ldst) \
  __builtin_amdgcn_global_load_lds((gbl_void_t*)(gsrc), (lds_void_t*)(ldst), 16, 0, 0)

DEVI unsigned short f2bf(float f) {
  unsigned int u = __float_as_uint(f);
  u += 0x7FFFu + ((u >> 16) & 1u);   // round-to-nearest-even
  return (unsigned short)(u >> 16);
}

DEVI unsigned int cvt_pk_bf16(float lo, float hi) {
  unsigned int r;
  asm("v_cvt_pk_bf16_f32 %0, %1, %2" : "=v"(r) : "v"(lo), "v"(hi));
  return r;
}

// ---------------------------------------------------------------------------
// All 4 weight transposes in one launch. in [K][N=512] f32 -> out [N][K] bf16.
// ---------------------------------------------------------------------------
__global__ __launch_bounds__(256) void wtrans_all_kernel(
    const float* __restrict__ wq, const float* __restrict__ wk,
    const float* __restrict__ wv, const float* __restrict__ wo,
    unsigned short* __restrict__ wqT, unsigned short* __restrict__ wkT,
    unsigned short* __restrict__ wvT, unsigned short* __restrict__ woT) {
  __shared__ float tile[32][33];
  int bid = blockIdx.x;
  const float* in;
  unsigned short* out;
  int K, r;
  if (bid < 256)       { in = wq; out = wqT; K = 512; r = bid; }
  else if (bid < 640)  { in = wk; out = wkT; K = 768; r = bid - 256; }
  else if (bid < 1024) { in = wv; out = wvT; K = 768; r = bid - 640; }
  else                 { in = wo; out = woT; K = 512; r = bid - 1024; }
  int n0 = (r & 15) * 32, k0 = (r >> 4) * 32;
  int tx = threadIdx.x, ty = threadIdx.y;
#pragma unroll
  for (int j = 0; j < 4; ++j)
    tile[ty * 4 + j][tx] = in[(size_t)(k0 + ty * 4 + j) * 512 + n0 + tx];
  __syncthreads();
#pragma unroll
  for (int j = 0; j < 4; ++j)
    out[(size_t)(n0 + ty * 4 + j) * K + k0 + tx] = f2bf(tile[tx][ty * 4 + j]);
}

// ---------------------------------------------------------------------------
// K/V projection (unchanged, proven)
// ---------------------------------------------------------------------------
__global__ __launch_bounds__(256) void kv_proj_kernel(const float* __restrict__ ctx,
                                                      const unsigned short* __restrict__ wkT,
                                                      const unsigned short* __restrict__ wvT,
                                                      const float* __restrict__ bk,
                                                      const float* __restrict__ bv,
                                                      unsigned short* __restrict__ Kp,
                                                      unsigned short* __restrict__ Vt) {
  __shared__ __align__(16) unsigned short As[64][40];
  __shared__ __align__(16) unsigned short Bs[64][40];
  int bid = blockIdx.x;
  int sel = bid / 80;
  int rem = bid % 80;
  int mt = rem / 8, nt = rem % 8;
  const unsigned short* wT = sel ? wvT : wkT;
  const float* bias = sel ? bv : bk;
  int tid = threadIdx.x;
  int l = tid & 63, w = tid >> 6;
  int lr = l & 15, lg = l >> 4;

  f32x4 acc[4] = {};
  for (int k0 = 0; k0 < 768; k0 += 32) {
#pragma unroll
    for (int it = 0; it < 2; ++it) {
      int idx4 = it * 256 + tid;
      int r = idx4 >> 3, q4 = idx4 & 7;
      int m = mt * 64 + r;
      float4 v = {0.f, 0.f, 0.f, 0.f};
      if (m < 616) v = *(const float4*)(ctx + (size_t)m * 768 + k0 + q4 * 4);
      ushort4 o;
      o.x = f2bf(v.x); o.y = f2bf(v.y); o.z = f2bf(v.z); o.w = f2bf(v.w);
      *(ushort4*)&As[r][q4 * 4] = o;
    }
    {
      int c = tid >> 2, q8 = tid & 3;
      *(uint4*)&Bs[c][q8 * 8] =
          *(const uint4*)(wT + (size_t)(nt * 64 + c) * 768 + k0 + q8 * 8);
    }
    __syncthreads();
    bf16x8 a = *(const bf16x8*)&As[w * 16 + lr][lg * 8];
#pragma unroll
    for (int n = 0; n < 4; ++n) {
      bf16x8 bb = *(const bf16x8*)&Bs[n * 16 + lr][lg * 8];
      acc[n] = __builtin_amdgcn_mfma_f32_16x16x32_bf16(a, bb, acc[n], 0, 0, 0);
    }
    __syncthreads();
  }
#pragma unroll
  for (int n = 0; n < 4; ++n) {
#pragma unroll
    for (int reg = 0; reg < 4; ++reg) {
      int m = mt * 64 + w * 16 + lg * 4 + reg;
      if (m < 616) {
        int bI = m / 77, s = m % 77;
        int col = nt * 64 + n * 16 + lr;
        int h = col >> 6, d = col & 63;
        float v = acc[n][reg] + bias[col];
        if (sel == 0)
          Kp[(((size_t)(bI * 8 + h)) * 80 + s) * 64 + d] = f2bf(v);
        else
          Vt[(((size_t)(bI * 8 + h)) * 64 + d) * 96 + s] = f2bf(v);
      }
    }
  }
}

// ---------------------------------------------------------------------------
// FUSED Q-proj + attention, v4 (barrier-free, direct-from-global operands).
// ---------------------------------------------------------------------------
__global__ __launch_bounds__(256, 3) void qproj_attn_kernel(
    const float* __restrict__ A32, const unsigned short* __restrict__ BT,
    const float* __restrict__ bias, const unsigned short* __restrict__ Kp,
    const unsigned short* __restrict__ Vt, unsigned short* __restrict__ Oq) {
  __shared__ __align__(16) char smem[36864];   // Qw [4][64][72] bf16

  // XCD-bijective swizzle: 1024 blocks, 8 XCDs, 128/XCD; the 4 N-tile
  // siblings of an A panel are consecutive -> same XCD L2.
  int bid = ((blockIdx.x & 7) << 7) | (blockIdx.x >> 3);
  size_t mbase = (size_t)(bid >> 2) * 128;
  int nbase = (bid & 3) * 128;
  int tid = threadIdx.x;
  int l = tid & 63, w = tid >> 6;
  int lr = l & 15, lg = l >> 4;
  int wr = (w >> 1) * 64, wc = (w & 1) * 64;

  // per-lane fragment base addresses (frag m at +m*16 rows)
  const float* gA = A32 + (mbase + wr + lr) * 512 + lg * 8;
  const unsigned short* gB = BT + (size_t)(nbase + wc + lr) * 512 + lg * 8;

  f32x4 acc[4][4] = {};
#pragma unroll
  for (int k0 = 0; k0 < 512; k0 += 32) {
    float4 a0[4], a1[4];
    bf16x8 bv8[4];
#pragma unroll
    for (int m = 0; m < 4; ++m) {
      a0[m] = *(const float4*)(gA + (size_t)m * 8192 + k0);
      a1[m] = *(const float4*)(gA + (size_t)m * 8192 + k0 + 4);
    }
#pragma unroll
    for (int n = 0; n < 4; ++n)
      bv8[n] = *(const bf16x8*)(gB + (size_t)n * 8192 + k0);
    bf16x8 af[4];
#pragma unroll
    for (int m = 0; m < 4; ++m) {
      unsigned int u0 = cvt_pk_bf16(a0[m].x, a0[m].y);
      unsigned int u1 = cvt_pk_bf16(a0[m].z, a0[m].w);
      unsigned int u2 = cvt_pk_bf16(a1[m].x, a1[m].y);
      unsigned int u3 = cvt_pk_bf16(a1[m].z, a1[m].w);
      uint4 uu = {u0, u1, u2, u3};
      af[m] = *(bf16x8*)&uu;
    }
#pragma unroll
    for (int m = 0; m < 4; ++m)
#pragma unroll
      for (int n = 0; n < 4; ++n)
        acc[m][n] = __builtin_amdgcn_mfma_f32_16x16x32_bf16(af[m], bv8[n], acc[m][n], 0, 0, 0);
  }

  // ---- epilogue: Q quadrant -> wave-private LDS (transpose), +bias ----
  unsigned short* Qme = (unsigned short*)smem + w * (64 * 72);
  float bb[4];
#pragma unroll
  for (int n = 0; n < 4; ++n) bb[n] = bias[nbase + wc + n * 16 + lr];
#pragma unroll
  for (int m = 0; m < 4; ++m)
#pragma unroll
    for (int n = 0; n < 4; ++n)
#pragma unroll
      for (int reg = 0; reg < 4; ++reg)
        Qme[(m * 16 + lg * 4 + reg) * 72 + n * 16 + lr] = f2bf(acc[m][n][reg] + bb[n]);

  // preload ALL Q frags to regs (wave-local LDS RAW: compiler orders)
  bf16x8 qf[4][2];
#pragma unroll
  for (int rg = 0; rg < 4; ++rg) {
    qf[rg][0] = *(const bf16x8*)&Qme[(rg * 16 + lr) * 72 + lg * 8];
    qf[rg][1] = *(const bf16x8*)&Qme[(rg * 16 + lr) * 72 + 32 + lg * 8];
  }

  // P buffer inside this wave's own (now dead) Qw region -> wave-private,
  // no cross-wave barrier needed. 16 rows x 104 cols bf16 = 3328 B <= 9216 B.
  unsigned short* Pme = Qme;
  for (int z = l; z < 256; z += 64) Pme[(z >> 4) * 104 + 80 + (z & 15)] = 0;

  // ---- wave-local attention: 64 q-rows x head h ----
  int b = (int)(mbase >> 12);
  int h = (bid & 3) * 2 + (w & 1);
  const unsigned short* Kph = Kp + (size_t)(b * 8 + h) * (80 * 64);
  const unsigned short* Vth = Vt + (size_t)(b * 8 + h) * (64 * 96);

  const float C = 0.125f * 1.44269504088896f;  // 1/sqrt(64) * log2(e)

  auto QK = [&](int rg, f32x4* s) {
#pragma unroll
    for (int t = 0; t < 5; ++t) {
      const unsigned short* kr = Kph + (t * 16 + lr) * 64 + lg * 8;
      bf16x8 k0 = *(const bf16x8*)kr;
      bf16x8 k1 = *(const bf16x8*)(kr + 32);
      s[t] = __builtin_amdgcn_mfma_f32_16x16x32_bf16(qf[rg][0], k0, s[t], 0, 0, 0);
      s[t] = __builtin_amdgcn_mfma_f32_16x16x32_bf16(qf[rg][1], k1, s[t], 0, 0, 0);
    }
    if (lr >= 13) {  // cols 64+lr >= 77 are pad
      s[4][0] = -1e30f; s[4][1] = -1e30f; s[4][2] = -1e30f; s[4][3] = -1e30f;
    }
  };

  f32x4 sc[5] = {};
  QK(0, sc);
#pragma unroll
  for (int rg = 0; rg < 4; ++rg) {
    float mx[4], sm[4];
#pragma unroll
    for (int r = 0; r < 4; ++r)
      mx[r] = fmaxf(fmaxf(fmaxf(sc[0][r], sc[1][r]), fmaxf(sc[2][r], sc[3][r])), sc[4][r]);
#pragma unroll
    for (int d = 1; d < 16; d <<= 1)
#pragma unroll
      for (int r = 0; r < 4; ++r) mx[r] = fmaxf(mx[r], __shfl_xor(mx[r], d, 64));
    float p[5][4];
#pragma unroll
    for (int t = 0; t < 5; ++t)
#pragma unroll
      for (int r = 0; r < 4; ++r) p[t][r] = exp2f((sc[t][r] - mx[r]) * C);
#pragma unroll
    for (int r = 0; r < 4; ++r)
      sm[r] = p[0][r] + p[1][r] + p[2][r] + p[3][r] + p[4][r];
#pragma unroll
    for (int d = 1; d < 16; d <<= 1)
#pragma unroll
      for (int r = 0; r < 4; ++r) sm[r] += __shfl_xor(sm[r], d, 64);
#pragma unroll
    for (int r = 0; r < 4; ++r) sm[r] = 1.0f / sm[r];
#pragma unroll
    for (int t = 0; t < 5; ++t)
#pragma unroll
      for (int r = 0; r < 4; ++r)
        Pme[(lg * 4 + r) * 104 + t * 16 + lr] = f2bf(p[t][r] * sm[r]);

    f32x4 sn[5] = {};
    if (rg < 3) QK(rg + 1, sn);

    bf16x8 ap[3];
#pragma unroll
    for (int c = 0; c < 3; ++c) ap[c] = *(const bf16x8*)&Pme[lr * 104 + c * 32 + lg * 8];
#pragma unroll
    for (int ct = 0; ct < 4; ++ct) {
      f32x4 o = {};
#pragma unroll
      for (int c = 0; c < 3; ++c) {
        bf16x8 vv = *(const bf16x8*)(Vth + (size_t)(ct * 16 + lr) * 96 + c * 32 + lg * 8);
        o = __builtin_amdgcn_mfma_f32_16x16x32_bf16(ap[c], vv, o, 0, 0, 0);
      }
#pragma unroll
      for (int reg = 0; reg < 4; ++reg)
        Oq[(mbase + wr + rg * 16 + lg * 4 + reg) * 512 + nbase + wc + ct * 16 + lr] =
            f2bf(o[reg]);
    }
#pragma unroll
    for (int t = 0; t < 5; ++t) sc[t] = sn[t];
  }
}

// ---------------------------------------------------------------------------
// m97-style GEMM for O-proj (+XCD swizzle): A[32768][512]bf16 @ woT + bo -> f32
// (unchanged from R5)
// ---------------------------------------------------------------------------
__global__ __launch_bounds__(256) void gemm512_glds_kernel(
    const unsigned short* __restrict__ A, const unsigned short* __restrict__ BT,
    const float* __restrict__ bias, float* __restrict__ Out) {
  __shared__ __align__(16) unsigned short As[128 * 32];
  __shared__ __align__(16) unsigned short Bs[128 * 32];
  int bid = ((blockIdx.x & 7) << 7) | (blockIdx.x >> 3);  // XCD swizzle
  size_t mbase = (size_t)(bid >> 2) * 128;
  int nbase = (bid & 3) * 128;
  int tid = threadIdx.x;
  int l = tid & 63, w = tid >> 6;
  int lr = l & 15, lg = l >> 4;
  int wr = (w >> 1) * 64, wc = (w & 1) * 64;

  const unsigned short* gA = A + (mbase + w * 32 + (l >> 2)) * 512 + (l & 3) * 8;
  const unsigned short* gB = BT + (size_t)(nbase + w * 32 + (l >> 2)) * 512 + (l & 3) * 8;
  unsigned short* lA = As + w * 1024;
  unsigned short* lB = Bs + w * 1024;

  f32x4 acc[4][4] = {};
  for (int k0 = 0; k0 < 512; k0 += 32) {
    GLDS16(gA + k0, lA);
    GLDS16(gA + k0 + 16 * 512, lA + 512);
    GLDS16(gB + k0, lB);
    GLDS16(gB + k0 + 16 * 512, lB + 512);
    asm volatile("s_waitcnt vmcnt(0)" ::: "memory");
    __syncthreads();
    bf16x8 af[4], bv8[4];
#pragma unroll
    for (int m = 0; m < 4; ++m)
      af[m] = *(const bf16x8*)&As[(wr + m * 16 + lr) * 32 + lg * 8];
#pragma unroll
    for (int n = 0; n < 4; ++n)
      bv8[n] = *(const bf16x8*)&Bs[(wc + n * 16 + lr) * 32 + lg * 8];
#pragma unroll
    for (int m = 0; m < 4; ++m)
#pragma unroll
      for (int n = 0; n < 4; ++n)
        acc[m][n] = __builtin_amdgcn_mfma_f32_16x16x32_bf16(af[m], bv8[n], acc[m][n], 0, 0, 0);
    __syncthreads();
  }
#pragma unroll
  for (int m = 0; m < 4; ++m) {
#pragma unroll
    for (int n = 0; n < 4; ++n) {
#pragma unroll
      for (int reg = 0; reg < 4; ++reg) {
        size_t row = mbase + wr + m * 16 + lg * 4 + reg;
        int col = nbase + wc + n * 16 + lr;
        Out[row * 512 + col] = acc[m][n][reg] + bias[col];
      }
    }
  }
}

// ---------------------------------------------------------------------------
// Workspace layout (bytes)
// ---------------------------------------------------------------------------
static const size_t OFF_Q   = 0;                         // 8*4096*512*2 = 33554432
static const size_t OFF_KP  = 33554432;                  // 8*8*80*64*2  = 655360
static const size_t OFF_VT  = OFF_KP + 655360;           // 8*8*64*96*2  = 786432
static const size_t OFF_WQT = OFF_VT + 786432;           // 512*512*2
static const size_t OFF_WKT = OFF_WQT + 524288;          // 512*768*2
static const size_t OFF_WVT = OFF_WKT + 786432;          // 512*768*2
static const size_t OFF_WOT = OFF_WVT + 786432;          // 512*512*2
static const size_t WS_NEEDED = OFF_WOT + 524288;        // 37617664

extern "C" void kernel_launch(void* const* d_in, const int* in_sizes, int n_in,
                              void* d_out, int out_size, void* d_ws, size_t ws_size,
                              hipStream_t stream) {
  (void)in_sizes; (void)n_in; (void)out_size;
  if (ws_size < WS_NEEDED) return;

  const float* latent  = (const float*)d_in[0];
  const float* context = (const float*)d_in[1];
  const float* wq = (const float*)d_in[2];
  const float* bq = (const float*)d_in[3];
  const float* wk = (const float*)d_in[4];
  const float* bk = (const float*)d_in[5];
  const float* wv = (const float*)d_in[6];
  const float* bv = (const float*)d_in[7];
  const float* wo = (const float*)d_in[8];
  const float* bo = (const float*)d_in[9];
  float* out = (float*)d_out;

  char* ws = (char*)d_ws;
  unsigned short* wsQ = (unsigned short*)(ws + OFF_Q);   // attn output (bf16)
  unsigned short* Kp  = (unsigned short*)(ws + OFF_KP);
  unsigned short* Vt  = (unsigned short*)(ws + OFF_VT);
  unsigned short* wqT = (unsigned short*)(ws + OFF_WQT);
  unsigned short* wkT = (unsigned short*)(ws + OFF_WKT);
  unsigned short* wvT = (unsigned short*)(ws + OFF_WVT);
  unsigned short* woT = (unsigned short*)(ws + OFF_WOT);

  wtrans_all_kernel<<<1280, dim3(32, 8), 0, stream>>>(wq, wk, wv, wo,
                                                      wqT, wkT, wvT, woT);
  hipMemsetAsync(ws + OFF_KP, 0, 655360 + 786432, stream);
  kv_proj_kernel<<<160, 256, 0, stream>>>(context, wkT, wvT, bk, bv, Kp, Vt);
  qproj_attn_kernel<<<1024, 256, 0, stream>>>(latent, wqT, bq, Kp, Vt, wsQ);
  gemm512_glds_kernel<<<1024, 256, 0, stream>>>(wsQ, woT, bo, out);
}

// Round 7
// 127.069 us; speedup vs baseline: 1.5062x; 1.5062x over previous
//
#include <hip/hip_runtime.h>

// CrossAttention on MI355X (gfx950), round 7.
// B=8 SQ=4096 SKV=77 DE=512 DC=768 H=8 DH=64.
// R7: revert R6's direct-from-global regression. Both GEMMs use the proven
// glds-width-16 staging, now 2-phase double-buffered (stage k+1 issued before
// MFMA of k, one vmcnt(0)+barrier per step). Separate latent cvt pass is
// back. Attn tail stays barrier-free (wave-private P) + deferred softmax
// normalization (scale after PV).

typedef __attribute__((ext_vector_type(8))) __bf16 bf16x8;
typedef __attribute__((ext_vector_type(4))) float f32x4;

#define DEVI static __device__ __forceinline__

typedef __attribute__((address_space(3))) void lds_void_t;
typedef const __attribute__((address_space(1))) void gbl_void_t;
#define GLDS16(gsrc, ldst) \
  __builtin_amdgcn_global_load_lds((gbl_void_t*)(gsrc), (lds_void_t*)(ldst), 16, 0, 0)

DEVI unsigned short f2bf(float f) {
  unsigned int u = __float_as_uint(f);
  u += 0x7FFFu + ((u >> 16) & 1u);   // round-to-nearest-even
  return (unsigned short)(u >> 16);
}

DEVI unsigned int pack2bf(float a, float b) {
  return (unsigned int)f2bf(a) | ((unsigned int)f2bf(b) << 16);
}

// ---------------------------------------------------------------------------
// latent fp32 -> bf16, 8 elems/thread
// ---------------------------------------------------------------------------
__global__ __launch_bounds__(256) void cvt_bf16_kernel(const float* __restrict__ in,
                                                       unsigned int* __restrict__ out4) {
  int i = blockIdx.x * 256 + threadIdx.x;
  const float4* in4 = (const float4*)in;
  float4 a = in4[2 * i];
  float4 b = in4[2 * i + 1];
  uint4 o;
  o.x = pack2bf(a.x, a.y);
  o.y = pack2bf(a.z, a.w);
  o.z = pack2bf(b.x, b.y);
  o.w = pack2bf(b.z, b.w);
  *(uint4*)(out4 + 4 * (size_t)i) = o;
}

// ---------------------------------------------------------------------------
// All 4 weight transposes in one launch. in [K][N=512] f32 -> out [N][K] bf16.
// ---------------------------------------------------------------------------
__global__ __launch_bounds__(256) void wtrans_all_kernel(
    const float* __restrict__ wq, const float* __restrict__ wk,
    const float* __restrict__ wv, const float* __restrict__ wo,
    unsigned short* __restrict__ wqT, unsigned short* __restrict__ wkT,
    unsigned short* __restrict__ wvT, unsigned short* __restrict__ woT) {
  __shared__ float tile[32][33];
  int bid = blockIdx.x;
  const float* in;
  unsigned short* out;
  int K, r;
  if (bid < 256)       { in = wq; out = wqT; K = 512; r = bid; }
  else if (bid < 640)  { in = wk; out = wkT; K = 768; r = bid - 256; }
  else if (bid < 1024) { in = wv; out = wvT; K = 768; r = bid - 640; }
  else                 { in = wo; out = woT; K = 512; r = bid - 1024; }
  int n0 = (r & 15) * 32, k0 = (r >> 4) * 32;
  int tx = threadIdx.x, ty = threadIdx.y;
#pragma unroll
  for (int j = 0; j < 4; ++j)
    tile[ty * 4 + j][tx] = in[(size_t)(k0 + ty * 4 + j) * 512 + n0 + tx];
  __syncthreads();
#pragma unroll
  for (int j = 0; j < 4; ++j)
    out[(size_t)(n0 + ty * 4 + j) * K + k0 + tx] = f2bf(tile[tx][ty * 4 + j]);
}

// ---------------------------------------------------------------------------
// K/V projection (unchanged, proven)
// ---------------------------------------------------------------------------
__global__ __launch_bounds__(256) void kv_proj_kernel(const float* __restrict__ ctx,
                                                      const unsigned short* __restrict__ wkT,
                                                      const unsigned short* __restrict__ wvT,
                                                      const float* __restrict__ bk,
                                                      const float* __restrict__ bv,
                                                      unsigned short* __restrict__ Kp,
                                                      unsigned short* __restrict__ Vt) {
  __shared__ __align__(16) unsigned short As[64][40];
  __shared__ __align__(16) unsigned short Bs[64][40];
  int bid = blockIdx.x;
  int sel = bid / 80;
  int rem = bid % 80;
  int mt = rem / 8, nt = rem % 8;
  const unsigned short* wT = sel ? wvT : wkT;
  const float* bias = sel ? bv : bk;
  int tid = threadIdx.x;
  int l = tid & 63, w = tid >> 6;
  int lr = l & 15, lg = l >> 4;

  f32x4 acc[4] = {};
  for (int k0 = 0; k0 < 768; k0 += 32) {
#pragma unroll
    for (int it = 0; it < 2; ++it) {
      int idx4 = it * 256 + tid;
      int r = idx4 >> 3, q4 = idx4 & 7;
      int m = mt * 64 + r;
      float4 v = {0.f, 0.f, 0.f, 0.f};
      if (m < 616) v = *(const float4*)(ctx + (size_t)m * 768 + k0 + q4 * 4);
      ushort4 o;
      o.x = f2bf(v.x); o.y = f2bf(v.y); o.z = f2bf(v.z); o.w = f2bf(v.w);
      *(ushort4*)&As[r][q4 * 4] = o;
    }
    {
      int c = tid >> 2, q8 = tid & 3;
      *(uint4*)&Bs[c][q8 * 8] =
          *(const uint4*)(wT + (size_t)(nt * 64 + c) * 768 + k0 + q8 * 8);
    }
    __syncthreads();
    bf16x8 a = *(const bf16x8*)&As[w * 16 + lr][lg * 8];
#pragma unroll
    for (int n = 0; n < 4; ++n) {
      bf16x8 bb = *(const bf16x8*)&Bs[n * 16 + lr][lg * 8];
      acc[n] = __builtin_amdgcn_mfma_f32_16x16x32_bf16(a, bb, acc[n], 0, 0, 0);
    }
    __syncthreads();
  }
#pragma unroll
  for (int n = 0; n < 4; ++n) {
#pragma unroll
    for (int reg = 0; reg < 4; ++reg) {
      int m = mt * 64 + w * 16 + lg * 4 + reg;
      if (m < 616) {
        int bI = m / 77, s = m % 77;
        int col = nt * 64 + n * 16 + lr;
        int h = col >> 6, d = col & 63;
        float v = acc[n][reg] + bias[col];
        if (sel == 0)
          Kp[(((size_t)(bI * 8 + h)) * 80 + s) * 64 + d] = f2bf(v);
        else
          Vt[(((size_t)(bI * 8 + h)) * 64 + d) * 96 + s] = f2bf(v);
      }
    }
  }
}

// ---------------------------------------------------------------------------
// FUSED Q-proj + attention, v5: both-glds 2-phase double-buffered GEMM +
// barrier-free attn tail with deferred softmax normalization.
// LDS: GEMM = [2][8KB] A + [2][8KB] B = 32KB; attn overlay Qw 36KB; total
// 36864 -> 4 blocks/CU.
// ---------------------------------------------------------------------------
__global__ __launch_bounds__(256, 4) void qproj_attn_kernel(
    const unsigned short* __restrict__ A, const unsigned short* __restrict__ BT,
    const float* __restrict__ bias, const unsigned short* __restrict__ Kp,
    const unsigned short* __restrict__ Vt, unsigned short* __restrict__ Oq) {
  __shared__ __align__(16) char smem[36864];
  unsigned short* As = (unsigned short*)smem;            // [2][128*32]
  unsigned short* Bs = (unsigned short*)(smem + 16384);  // [2][128*32]

  // XCD-bijective swizzle (1024 blocks, 8 XCDs): A-panel siblings contiguous.
  int bid = ((blockIdx.x & 7) << 7) | (blockIdx.x >> 3);
  size_t mbase = (size_t)(bid >> 2) * 128;
  int nbase = (bid & 3) * 128;
  int tid = threadIdx.x;
  int l = tid & 63, w = tid >> 6;
  int lr = l & 15, lg = l >> 4;
  int wr = (w >> 1) * 64, wc = (w & 1) * 64;

  const unsigned short* gA = A + (mbase + w * 32 + (l >> 2)) * 512 + (l & 3) * 8;
  const unsigned short* gB = BT + (size_t)(nbase + w * 32 + (l >> 2)) * 512 + (l & 3) * 8;

  // prologue: stage k0=0 into buf0
  GLDS16(gA, As + w * 1024);
  GLDS16(gA + 16 * 512, As + w * 1024 + 512);
  GLDS16(gB, Bs + w * 1024);
  GLDS16(gB + 16 * 512, Bs + w * 1024 + 512);
  asm volatile("s_waitcnt vmcnt(0)" ::: "memory");
  __syncthreads();

  f32x4 acc[4][4] = {};
#pragma unroll
  for (int k0 = 0; k0 < 512; k0 += 32) {
    const int cur = (k0 >> 5) & 1;
    const int nxt = cur ^ 1;
    if (k0 < 480) {  // issue next-step staging FIRST (flight covered by MFMA)
      GLDS16(gA + k0 + 32, As + nxt * 4096 + w * 1024);
      GLDS16(gA + k0 + 32 + 16 * 512, As + nxt * 4096 + w * 1024 + 512);
      GLDS16(gB + k0 + 32, Bs + nxt * 4096 + w * 1024);
      GLDS16(gB + k0 + 32 + 16 * 512, Bs + nxt * 4096 + w * 1024 + 512);
    }
    const unsigned short* curA = As + cur * 4096;
    const unsigned short* curB = Bs + cur * 4096;
    bf16x8 af[4], bv8[4];
#pragma unroll
    for (int m = 0; m < 4; ++m)
      af[m] = *(const bf16x8*)&curA[(wr + m * 16 + lr) * 32 + lg * 8];
#pragma unroll
    for (int n = 0; n < 4; ++n)
      bv8[n] = *(const bf16x8*)&curB[(wc + n * 16 + lr) * 32 + lg * 8];
#pragma unroll
    for (int m = 0; m < 4; ++m)
#pragma unroll
      for (int n = 0; n < 4; ++n)
        acc[m][n] = __builtin_amdgcn_mfma_f32_16x16x32_bf16(af[m], bv8[n], acc[m][n], 0, 0, 0);
    asm volatile("s_waitcnt vmcnt(0)" ::: "memory");
    __syncthreads();
  }

  // ---- epilogue: Q quadrant -> wave-private LDS (transpose), +bias ----
  // After the loop's final barrier all ds_reads are done -> overlay is safe.
  unsigned short* Qme = (unsigned short*)smem + w * (64 * 72);
  float bb[4];
#pragma unroll
  for (int n = 0; n < 4; ++n) bb[n] = bias[nbase + wc + n * 16 + lr];
#pragma unroll
  for (int m = 0; m < 4; ++m)
#pragma unroll
    for (int n = 0; n < 4; ++n)
#pragma unroll
      for (int reg = 0; reg < 4; ++reg)
        Qme[(m * 16 + lg * 4 + reg) * 72 + n * 16 + lr] = f2bf(acc[m][n][reg] + bb[n]);

  // preload ALL Q frags to regs (wave-local LDS RAW: compiler orders)
  bf16x8 qf[4][2];
#pragma unroll
  for (int rg = 0; rg < 4; ++rg) {
    qf[rg][0] = *(const bf16x8*)&Qme[(rg * 16 + lr) * 72 + lg * 8];
    qf[rg][1] = *(const bf16x8*)&Qme[(rg * 16 + lr) * 72 + 32 + lg * 8];
  }

  // wave-private P inside this wave's dead Qw region (16 x 104 bf16)
  unsigned short* Pme = Qme;
  for (int z = l; z < 256; z += 64) Pme[(z >> 4) * 104 + 80 + (z & 15)] = 0;

  // ---- wave-local attention: 64 q-rows x head h ----
  int b = (int)(mbase >> 12);
  int h = (bid & 3) * 2 + (w & 1);
  const unsigned short* Kph = Kp + (size_t)(b * 8 + h) * (80 * 64);
  const unsigned short* Vth = Vt + (size_t)(b * 8 + h) * (64 * 96);

  const float C = 0.125f * 1.44269504088896f;  // 1/sqrt(64) * log2(e)

  auto QK = [&](int rg, f32x4* s) {
#pragma unroll
    for (int t = 0; t < 5; ++t) {
      const unsigned short* kr = Kph + (t * 16 + lr) * 64 + lg * 8;
      bf16x8 k0 = *(const bf16x8*)kr;
      bf16x8 k1 = *(const bf16x8*)(kr + 32);
      s[t] = __builtin_amdgcn_mfma_f32_16x16x32_bf16(qf[rg][0], k0, s[t], 0, 0, 0);
      s[t] = __builtin_amdgcn_mfma_f32_16x16x32_bf16(qf[rg][1], k1, s[t], 0, 0, 0);
    }
    if (lr >= 13) {  // cols 64+lr >= 77 are pad
      s[4][0] = -1e30f; s[4][1] = -1e30f; s[4][2] = -1e30f; s[4][3] = -1e30f;
    }
  };

  f32x4 sc[5] = {};
  QK(0, sc);
#pragma unroll
  for (int rg = 0; rg < 4; ++rg) {
    // row max (rows = lg*4+r)
    float mx[4];
#pragma unroll
    for (int r = 0; r < 4; ++r)
      mx[r] = fmaxf(fmaxf(fmaxf(sc[0][r], sc[1][r]), fmaxf(sc[2][r], sc[3][r])), sc[4][r]);
#pragma unroll
    for (int d = 1; d < 16; d <<= 1)
#pragma unroll
      for (int r = 0; r < 4; ++r) mx[r] = fmaxf(mx[r], __shfl_xor(mx[r], d, 64));
    // unnormalized exp -> P (normalization deferred to after PV)
    float p[5][4];
#pragma unroll
    for (int t = 0; t < 5; ++t)
#pragma unroll
      for (int r = 0; r < 4; ++r) p[t][r] = exp2f((sc[t][r] - mx[r]) * C);
#pragma unroll
    for (int t = 0; t < 5; ++t)
#pragma unroll
      for (int r = 0; r < 4; ++r)
        Pme[(lg * 4 + r) * 104 + t * 16 + lr] = f2bf(p[t][r]);

    // row sum (overlaps with P-write latency + PV MFMA issue below)
    float sm[4];
#pragma unroll
    for (int r = 0; r < 4; ++r)
      sm[r] = p[0][r] + p[1][r] + p[2][r] + p[3][r] + p[4][r];
#pragma unroll
    for (int d = 1; d < 16; d <<= 1)
#pragma unroll
      for (int r = 0; r < 4; ++r) sm[r] += __shfl_xor(sm[r], d, 64);
    float rs[4];
#pragma unroll
    for (int r = 0; r < 4; ++r) rs[r] = 1.0f / sm[r];

    // next QK (pure-reg MFMA + L1-hot K loads) overlaps softmax/PV
    f32x4 sn[5] = {};
    if (rg < 3) QK(rg + 1, sn);

    bf16x8 ap[3];
#pragma unroll
    for (int c = 0; c < 3; ++c) ap[c] = *(const bf16x8*)&Pme[lr * 104 + c * 32 + lg * 8];
#pragma unroll
    for (int ct = 0; ct < 4; ++ct) {
      f32x4 o = {};
#pragma unroll
      for (int c = 0; c < 3; ++c) {
        bf16x8 vv = *(const bf16x8*)(Vth + (size_t)(ct * 16 + lr) * 96 + c * 32 + lg * 8);
        o = __builtin_amdgcn_mfma_f32_16x16x32_bf16(ap[c], vv, o, 0, 0, 0);
      }
#pragma unroll
      for (int reg = 0; reg < 4; ++reg)
        Oq[(mbase + wr + rg * 16 + lg * 4 + reg) * 512 + nbase + wc + ct * 16 + lr] =
            f2bf(o[reg] * rs[reg]);
    }
#pragma unroll
    for (int t = 0; t < 5; ++t) sc[t] = sn[t];
  }
}

// ---------------------------------------------------------------------------
// O-proj GEMM: 2-phase double-buffered glds + XCD swizzle.
// A [32768][512] bf16 @ woT [512][512] bf16 + bo -> f32. LDS 32KB.
// ---------------------------------------------------------------------------
__global__ __launch_bounds__(256) void gemm512_glds_kernel(
    const unsigned short* __restrict__ A, const unsigned short* __restrict__ BT,
    const float* __restrict__ bias, float* __restrict__ Out) {
  __shared__ __align__(16) unsigned short As[2][128 * 32];
  __shared__ __align__(16) unsigned short Bs[2][128 * 32];
  int bid = ((blockIdx.x & 7) << 7) | (blockIdx.x >> 3);  // XCD swizzle
  size_t mbase = (size_t)(bid >> 2) * 128;
  int nbase = (bid & 3) * 128;
  int tid = threadIdx.x;
  int l = tid & 63, w = tid >> 6;
  int lr = l & 15, lg = l >> 4;
  int wr = (w >> 1) * 64, wc = (w & 1) * 64;

  const unsigned short* gA = A + (mbase + w * 32 + (l >> 2)) * 512 + (l & 3) * 8;
  const unsigned short* gB = BT + (size_t)(nbase + w * 32 + (l >> 2)) * 512 + (l & 3) * 8;

  GLDS16(gA, As[0] + w * 1024);
  GLDS16(gA + 16 * 512, As[0] + w * 1024 + 512);
  GLDS16(gB, Bs[0] + w * 1024);
  GLDS16(gB + 16 * 512, Bs[0] + w * 1024 + 512);
  asm volatile("s_waitcnt vmcnt(0)" ::: "memory");
  __syncthreads();

  f32x4 acc[4][4] = {};
#pragma unroll
  for (int k0 = 0; k0 < 512; k0 += 32) {
    const int cur = (k0 >> 5) & 1;
    const int nxt = cur ^ 1;
    if (k0 < 480) {
      GLDS16(gA + k0 + 32, As[nxt] + w * 1024);
      GLDS16(gA + k0 + 32 + 16 * 512, As[nxt] + w * 1024 + 512);
      GLDS16(gB + k0 + 32, Bs[nxt] + w * 1024);
      GLDS16(gB + k0 + 32 + 16 * 512, Bs[nxt] + w * 1024 + 512);
    }
    bf16x8 af[4], bv8[4];
#pragma unroll
    for (int m = 0; m < 4; ++m)
      af[m] = *(const bf16x8*)&As[cur][(wr + m * 16 + lr) * 32 + lg * 8];
#pragma unroll
    for (int n = 0; n < 4; ++n)
      bv8[n] = *(const bf16x8*)&Bs[cur][(wc + n * 16 + lr) * 32 + lg * 8];
#pragma unroll
    for (int m = 0; m < 4; ++m)
#pragma unroll
      for (int n = 0; n < 4; ++n)
        acc[m][n] = __builtin_amdgcn_mfma_f32_16x16x32_bf16(af[m], bv8[n], acc[m][n], 0, 0, 0);
    asm volatile("s_waitcnt vmcnt(0)" ::: "memory");
    __syncthreads();
  }
#pragma unroll
  for (int m = 0; m < 4; ++m) {
#pragma unroll
    for (int n = 0; n < 4; ++n) {
#pragma unroll
      for (int reg = 0; reg < 4; ++reg) {
        size_t row = mbase + wr + m * 16 + lg * 4 + reg;
        int col = nbase + wc + n * 16 + lr;
        Out[row * 512 + col] = acc[m][n][reg] + bias[col];
      }
    }
  }
}

// ---------------------------------------------------------------------------
// Workspace layout (bytes)
// ---------------------------------------------------------------------------
static const size_t OFF_Q   = 0;                         // 8*4096*512*2 = 33554432
static const size_t OFF_KP  = 33554432;                  // 8*8*80*64*2  = 655360
static const size_t OFF_VT  = OFF_KP + 655360;           // 8*8*64*96*2  = 786432
static const size_t OFF_WQT = OFF_VT + 786432;           // 512*512*2
static const size_t OFF_WKT = OFF_WQT + 524288;          // 512*768*2
static const size_t OFF_WVT = OFF_WKT + 786432;          // 512*768*2
static const size_t OFF_WOT = OFF_WVT + 786432;          // 512*512*2
static const size_t WS_NEEDED = OFF_WOT + 524288;        // 37617664

extern "C" void kernel_launch(void* const* d_in, const int* in_sizes, int n_in,
                              void* d_out, int out_size, void* d_ws, size_t ws_size,
                              hipStream_t stream) {
  (void)in_sizes; (void)n_in; (void)out_size;
  if (ws_size < WS_NEEDED) return;

  const float* latent  = (const float*)d_in[0];
  const float* context = (const float*)d_in[1];
  const float* wq = (const float*)d_in[2];
  const float* bq = (const float*)d_in[3];
  const float* wk = (const float*)d_in[4];
  const float* bk = (const float*)d_in[5];
  const float* wv = (const float*)d_in[6];
  const float* bv = (const float*)d_in[7];
  const float* wo = (const float*)d_in[8];
  const float* bo = (const float*)d_in[9];
  float* out = (float*)d_out;

  char* ws = (char*)d_ws;
  unsigned short* wsQ = (unsigned short*)(ws + OFF_Q);   // attn output (bf16)
  unsigned short* Kp  = (unsigned short*)(ws + OFF_KP);
  unsigned short* Vt  = (unsigned short*)(ws + OFF_VT);
  unsigned short* wqT = (unsigned short*)(ws + OFF_WQT);
  unsigned short* wkT = (unsigned short*)(ws + OFF_WKT);
  unsigned short* wvT = (unsigned short*)(ws + OFF_WVT);
  unsigned short* woT = (unsigned short*)(ws + OFF_WOT);

  // latent bf16 parked in d_out (first 33.5MB); consumed by qproj, then
  // d_out fully rewritten by the final GEMM.
  unsigned short* latBF = (unsigned short*)d_out;

  wtrans_all_kernel<<<1280, dim3(32, 8), 0, stream>>>(wq, wk, wv, wo,
                                                      wqT, wkT, wvT, woT);
  hipMemsetAsync(ws + OFF_KP, 0, 655360 + 786432, stream);
  kv_proj_kernel<<<160, 256, 0, stream>>>(context, wkT, wvT, bk, bv, Kp, Vt);
  cvt_bf16_kernel<<<8192, 256, 0, stream>>>(latent, (unsigned int*)latBF);
  qproj_attn_kernel<<<1024, 256, 0, stream>>>(latBF, wqT, bq, Kp, Vt, wsQ);
  gemm512_glds_kernel<<<1024, 256, 0, stream>>>(wsQ, woT, bo, out);
}